// Round 4
// baseline (47094.080 us; speedup 1.0000x reference)
//
#include <hip/hip_runtime.h>

typedef unsigned short u16;
typedef unsigned int u32;
typedef __attribute__((ext_vector_type(8))) short s16x8;
typedef __attribute__((ext_vector_type(4))) float f32x4;

#define MFMA_BF16 __builtin_amdgcn_mfma_f32_16x16x32_bf16
#define SCOPE_AGT __HIP_MEMORY_SCOPE_AGENT

__device__ __forceinline__ float sigf(float x) { return 1.f / (1.f + __expf(-x)); }
__device__ __forceinline__ float tanh_fast(float x) {
    float e = __expf(2.f * x);
    return 1.f - 2.f / (e + 1.f);
}
__device__ __forceinline__ u16 bf16_rn(float x) {
    u32 u = __float_as_uint(x);
    u += 0x7FFFu + ((u >> 16) & 1u);
    return (u16)(u >> 16);
}
__device__ __forceinline__ void split_store(float v, u16* __restrict__ ph,
                                            u16* __restrict__ pl, size_t off) {
    u16 h = bf16_rn(v);
    float hf = __uint_as_float(((u32)h) << 16);
    ph[off] = h;
    pl[off] = bf16_rn(v - hf);
}
__device__ __forceinline__ void mma3(f32x4& acc, s16x8 ah, s16x8 al, s16x8 wh, s16x8 wl) {
    acc = MFMA_BF16(ah, wh, acc, 0, 0, 0);
    acc = MFMA_BF16(al, wh, acc, 0, 0, 0);
    acc = MFMA_BF16(ah, wl, acc, 0, 0, 0);
}

// ---------------- weight prep: fragment-linear bf16 hi/lo ----------------
__global__ __launch_bounds__(256) void prep_w(const float* __restrict__ S1, int ld1, int K1,
                                              const float* __restrict__ S2, int ld2,
                                              u16* __restrict__ out, int NF) {
    int idx = blockIdx.x * 256 + threadIdx.x;
    int l = idx & 63;
    int sf = idx >> 6;
    int f = sf % NF;
    int s = sf / NF;
    int n = f * 16 + (l & 15);
    int kb = s * 32 + ((l >> 4) << 3);
    u16* o = out + (size_t)idx * 16;
#pragma unroll
    for (int j = 0; j < 8; ++j) {
        int k = kb + j;
        float v = (k < K1) ? S1[(size_t)n * ld1 + k] : S2[(size_t)n * ld2 + (k - K1)];
        u16 h = bf16_rn(v);
        float hf = __uint_as_float(((u32)h) << 16);
        o[j] = h;
        o[8 + j] = bf16_rn(v - hf);
    }
}

// ---------------- activation prep: f32 -> hi/lo planes ----------------
__global__ __launch_bounds__(256) void prep_act(const float* __restrict__ in,
                                                u16* __restrict__ hi, u16* __restrict__ lo,
                                                int n4) {
    int i = blockIdx.x * 256 + threadIdx.x;
    if (i >= n4) return;
    float4 v = ((const float4*)in)[i];
    float vv[4] = {v.x, v.y, v.z, v.w};
    u16 h[4], l[4];
#pragma unroll
    for (int j = 0; j < 4; ++j) {
        h[j] = bf16_rn(vv[j]);
        float hf = __uint_as_float(((u32)h[j]) << 16);
        l[j] = bf16_rn(vv[j] - hf);
    }
    ((ushort4*)hi)[i] = make_ushort4(h[0], h[1], h[2], h[3]);
    ((ushort4*)lo)[i] = make_ushort4(l[0], l[1], l[2], l[3]);
}

// ---------------- device-wide barrier (distributed flags, monotonic epoch) ----------------
__device__ __forceinline__ void gbar(u32* bar, int k) {
    __syncthreads();
    if (threadIdx.x == 0) {
        __threadfence();
        __hip_atomic_store(&bar[blockIdx.x * 16], (u32)k, __ATOMIC_RELEASE, SCOPE_AGT);
    }
    if (threadIdx.x < 256) {
        while (__hip_atomic_load(&bar[threadIdx.x * 16], __ATOMIC_ACQUIRE, SCOPE_AGT) < (u32)k)
            __builtin_amdgcn_s_sleep(16);
    }
    __syncthreads();
}

// ---------------- params ----------------
struct AllP {
    const u16 *Xh, *Xl, *Yh, *Yl;
    const float* ebi[4];
    const float* ebh[4];
    const float *b19, *b21, *b23, *b25, *b28, *b29, *b31, *b33, *b35;
    const u16* Wenc[4];
    const u16 *Wm1, *Wm2, *Wmu, *Wlv, *Wcg, *Wdg, *Wd1, *Wd2, *Wdo;
    u16 *encHh, *encHl;
    float* encC;
    u16 *HXYh, *HXYl, *H1h, *H1l, *H2h, *H2l, *muh, *mul2, *Ydh, *Ydl, *decHh, *decHl;
    float *CGf, *decC;
    float *outY, *muF, *lvF;
    u32* bar;
};

// ---------------- generic wave GEMM phase (rf1, CF col-frags) ----------------
template <int CF, int ACT>
__device__ __forceinline__ void phase_gemm(
    int ntiles, int g0, int l, int lr, int lk8, int l4,
    const u16* __restrict__ A1h, const u16* __restrict__ A1l, int ld1, int K1,
    const u16* __restrict__ A2h, const u16* __restrict__ A2l, int ld2,
    const u16* __restrict__ Wp, int NF, int NS,
    const float* __restrict__ b1, const float* __restrict__ b2,
    float* __restrict__ outF, int ldo,
    u16* __restrict__ Oh, u16* __restrict__ Ol, int ldop) {
    const s16x8* wp = (const s16x8*)Wp;
    for (int tile = g0; tile < ntiles; tile += 2048) {
        int rt = tile & 63, ct = tile >> 6;
        int row = rt * 16 + lr;
        f32x4 acc[CF];
#pragma unroll
        for (int cf = 0; cf < CF; ++cf) acc[cf] = (f32x4){0.f, 0.f, 0.f, 0.f};
        for (int s = 0; s < NS; ++s) {
            int kb = s * 32 + lk8;
            const u16 *ph, *pl2;
            size_t off;
            if (kb < K1) { ph = A1h; pl2 = A1l; off = (size_t)row * ld1 + kb; }
            else { ph = A2h; pl2 = A2l; off = (size_t)row * ld2 + (kb - K1); }
            s16x8 ah = *(const s16x8*)(ph + off), al = *(const s16x8*)(pl2 + off);
#pragma unroll
            for (int cf = 0; cf < CF; ++cf) {
                size_t wi = ((size_t)(s * NF + ct * CF + cf) * 64 + l) * 2;
                mma3(acc[cf], ah, al, wp[wi], wp[wi + 1]);
            }
        }
#pragma unroll
        for (int cf = 0; cf < CF; ++cf) {
            int col = ct * CF * 16 + cf * 16 + lr;
            float bv = (b1 ? b1[col] : 0.f) + (b2 ? b2[col] : 0.f);
#pragma unroll
            for (int r = 0; r < 4; ++r) {
                float v = acc[cf][r] + bv;
                if (ACT) v = tanh_fast(v);
                int rw = rt * 16 + l4 + r;
                if (outF) outF[(size_t)rw * ldo + col] = v;
                if (Oh) split_store(v, Oh, Ol, (size_t)rw * ldop + col);
            }
        }
    }
}

// ---------------- the persistent kernel ----------------
__global__ __launch_bounds__(512, 4) void vae_persist(AllP P) {
    const int tid = threadIdx.x, b = blockIdx.x;
    const int wid = tid >> 6, l = tid & 63;
    const int gid = b * 8 + wid;
    const int lr = l & 15, lk8 = (l >> 4) * 8, l4 = (l >> 4) * 4;
    int bk = 1;

    // ================= encoder =================
    {
        const int scan = b >> 6;
        const int ct = (b >> 3) & 7;
        const int rt = ((b & 7) << 3) + wid;  // 0..63
        const int T = (scan < 2) ? 64 : 100;
        const int rev = scan & 1;
        const u16* Xh_ = (scan < 2) ? P.Xh : P.Yh;
        const u16* Xl_ = (scan < 2) ? P.Xl : P.Yl;
        const s16x8* wp = (const s16x8*)P.Wenc[scan];
        const float* bi = P.ebi[scan];
        const float* bh = P.ebh[scan];
        u16* Hhb = P.encHh + (size_t)scan * 2 * 1024 * 256;
        u16* Hlb = P.encHl + (size_t)scan * 2 * 1024 * 256;
        float* Cs = P.encC + (size_t)scan * 1024 * 256;
        const int row = rt * 16 + lr;
        const int hc0 = ct * 32;
        float hsr[2][4] = {};

        for (int t = 0; t < 100; ++t) {
            if (t < T) {
                int tt = rev ? (T - 1 - t) : t;
                const u16* xh = Xh_ + (size_t)tt * 1024 * 64;
                const u16* xl = Xl_ + (size_t)tt * 1024 * 64;
                const u16* Hch = Hhb + (size_t)(t & 1) * 1024 * 256;
                const u16* Hcl = Hlb + (size_t)(t & 1) * 1024 * 256;
                u16* Hnh = Hhb + (size_t)((t + 1) & 1) * 1024 * 256;
                u16* Hnl = Hlb + (size_t)((t + 1) & 1) * 1024 * 256;
                f32x4 acc[4][2];
#pragma unroll
                for (int q = 0; q < 4; ++q)
#pragma unroll
                    for (int cf = 0; cf < 2; ++cf) {
                        int col = q * 256 + hc0 + cf * 16 + lr;
                        float bv = bi[col] + bh[col];
                        acc[q][cf] = (f32x4){bv, bv, bv, bv};
                    }
                int NS = (t == 0) ? 2 : 10;
                for (int s = 0; s < NS; ++s) {
                    int kb = s * 32 + lk8;
                    const u16 *ph, *pl2;
                    size_t off;
                    if (kb < 64) { ph = xh; pl2 = xl; off = (size_t)row * 64 + kb; }
                    else { ph = Hch; pl2 = Hcl; off = (size_t)row * 256 + (kb - 64); }
                    s16x8 ah = *(const s16x8*)(ph + off), al = *(const s16x8*)(pl2 + off);
#pragma unroll
                    for (int q = 0; q < 4; ++q)
#pragma unroll
                        for (int cf = 0; cf < 2; ++cf) {
                            size_t wi = ((size_t)(s * 64 + q * 16 + ct * 2 + cf) * 64 + l) * 2;
                            mma3(acc[q][cf], ah, al, wp[wi], wp[wi + 1]);
                        }
                }
#pragma unroll
                for (int cf = 0; cf < 2; ++cf) {
                    int hc = hc0 + cf * 16 + lr;
#pragma unroll
                    for (int r = 0; r < 4; ++r) {
                        int rw = rt * 16 + l4 + r;
                        size_t co = (size_t)rw * 256 + hc;
                        float gi = sigf(acc[0][cf][r]);
                        float gf = sigf(acc[1][cf][r]);
                        float gg = tanh_fast(acc[2][cf][r]);
                        float go = sigf(acc[3][cf][r]);
                        float cold = (t == 0) ? 0.f : Cs[co];
                        float cn = gf * cold + gi * gg;
                        float hn = go * tanh_fast(cn);
                        Cs[co] = cn;
                        split_store(hn, Hnh, Hnl, co);
                        hsr[cf][r] += hn;
                    }
                }
            }
            gbar(P.bar, bk++);
        }
        // means -> HXY planes
        float sc = (scan < 2) ? (1.f / 64.f) : (1.f / 100.f);
#pragma unroll
        for (int cf = 0; cf < 2; ++cf) {
            int hc = hc0 + cf * 16 + lr;
#pragma unroll
            for (int r = 0; r < 4; ++r) {
                int rw = rt * 16 + l4 + r;
                split_store(hsr[cf][r] * sc, P.HXYh, P.HXYl,
                            (size_t)rw * 1024 + scan * 256 + hc);
            }
        }
    }
    gbar(P.bar, bk++);

    // ================= encoder MLP + heads + CG =================
    phase_gemm<2, 1>(2048, gid, l, lr, lk8, l4,
                     P.HXYh, P.HXYl, 1024, 1024, P.HXYh, P.HXYl, 1024,
                     P.Wm1, 64, 32, P.b19, nullptr,
                     nullptr, 0, P.H1h, P.H1l, 1024);
    gbar(P.bar, bk++);
    phase_gemm<2, 1>(1024, gid, l, lr, lk8, l4,
                     P.H1h, P.H1l, 1024, 1024, P.H1h, P.H1l, 1024,
                     P.Wm2, 32, 32, P.b21, nullptr,
                     nullptr, 0, P.H2h, P.H2l, 512);
    gbar(P.bar, bk++);
    if (gid < 512) {
        int head = gid >> 8;
        phase_gemm<2, 0>(256, gid & 255, l, lr, lk8, l4,
                         P.H2h, P.H2l, 512, 512, P.H2h, P.H2l, 512,
                         head ? P.Wlv : P.Wmu, 8, 16,
                         head ? P.b25 : P.b23, nullptr,
                         head ? P.lvF : P.muF, 128,
                         head ? nullptr : P.muh, head ? nullptr : P.mul2, 128);
    }
    gbar(P.bar, bk++);
    phase_gemm<2, 0>(4096, gid, l, lr, lk8, l4,
                     P.HXYh, P.HXYl, 1024, 512, P.muh, P.mul2, 128,
                     P.Wcg, 128, 20, P.b28, P.b29,
                     P.CGf, 2048, nullptr, nullptr, 0);
    gbar(P.bar, bk++);

    // ================= decoder =================
    {
        const int rt = gid & 63;       // row tile (16 rows)
        const int hct = gid >> 6;      // 0..31, 16 h-cols each
        const int row = rt * 16 + lr;
        const int hc = hct * 16 + lr;
        const s16x8* wp = (const s16x8*)P.Wdg;

        for (int t = 0; t < 100; ++t) {
            // ---- gates + cell ----
            {
                const u16* yph = (t == 0) ? (P.Xh + (size_t)63 * 1024 * 64) : P.Ydh;
                const u16* ypl = (t == 0) ? (P.Xl + (size_t)63 * 1024 * 64) : P.Ydl;
                const u16* Hch = P.decHh + (size_t)(t & 1) * 1024 * 512;
                const u16* Hcl = P.decHl + (size_t)(t & 1) * 1024 * 512;
                u16* Hnh = P.decHh + (size_t)((t + 1) & 1) * 1024 * 512;
                u16* Hnl = P.decHl + (size_t)((t + 1) & 1) * 1024 * 512;
                f32x4 acc[4];
#pragma unroll
                for (int q = 0; q < 4; ++q)
#pragma unroll
                    for (int r = 0; r < 4; ++r)
                        acc[q][r] = P.CGf[(size_t)(rt * 16 + l4 + r) * 2048 +
                                          q * 512 + hct * 16 + lr];
                int NS = (t == 0) ? 2 : 18;
                for (int s = 0; s < NS; ++s) {
                    int kb = s * 32 + lk8;
                    const u16 *ph, *pl2;
                    size_t off;
                    if (kb < 64) { ph = yph; pl2 = ypl; off = (size_t)row * 64 + kb; }
                    else { ph = Hch; pl2 = Hcl; off = (size_t)row * 512 + (kb - 64); }
                    s16x8 ah = *(const s16x8*)(ph + off), al = *(const s16x8*)(pl2 + off);
#pragma unroll
                    for (int q = 0; q < 4; ++q) {
                        size_t wi = ((size_t)(s * 128 + q * 32 + hct) * 64 + l) * 2;
                        mma3(acc[q], ah, al, wp[wi], wp[wi + 1]);
                    }
                }
#pragma unroll
                for (int r = 0; r < 4; ++r) {
                    int rw = rt * 16 + l4 + r;
                    size_t co = (size_t)rw * 512 + hc;
                    float gi = sigf(acc[0][r]);
                    float gf = sigf(acc[1][r]);
                    float gg = tanh_fast(acc[2][r]);
                    float go = sigf(acc[3][r]);
                    float cold = (t == 0) ? 0.f : P.decC[co];
                    float cn = gf * cold + gi * gg;
                    float hn = go * tanh_fast(cn);
                    P.decC[co] = cn;
                    split_store(hn, Hnh, Hnl, co);
                }
            }
            gbar(P.bar, bk++);
            const u16* Hnh = P.decHh + (size_t)((t + 1) & 1) * 1024 * 512;
            const u16* Hnl = P.decHl + (size_t)((t + 1) & 1) * 1024 * 512;
            phase_gemm<2, 1>(2048, gid, l, lr, lk8, l4,
                             Hnh, Hnl, 512, 512, Hnh, Hnl, 512,
                             P.Wd1, 64, 16, P.b31, nullptr,
                             nullptr, 0, P.H1h, P.H1l, 1024);
            gbar(P.bar, bk++);
            phase_gemm<2, 1>(1024, gid, l, lr, lk8, l4,
                             P.H1h, P.H1l, 1024, 1024, P.H1h, P.H1l, 1024,
                             P.Wd2, 32, 32, P.b33, nullptr,
                             nullptr, 0, P.H2h, P.H2l, 512);
            gbar(P.bar, bk++);
            phase_gemm<2, 0>(128, gid, l, lr, lk8, l4,
                             P.H2h, P.H2l, 512, 512, P.H2h, P.H2l, 512,
                             P.Wdo, 4, 16, P.b35, nullptr,
                             P.outY + (size_t)t * 1024 * 64, 64, P.Ydh, P.Ydl, 64);
            gbar(P.bar, bk++);
        }
    }
}

// ---------------- host ----------------
extern "C" void kernel_launch(void* const* d_in, const int* in_sizes, int n_in,
                              void* d_out, int out_size, void* d_ws, size_t ws_size,
                              hipStream_t stream) {
    (void)in_sizes; (void)n_in; (void)out_size; (void)ws_size;
    auto F = [&](int i) { return (const float*)d_in[i]; };
    const float* x = F(0);
    const float* y = F(1);
    float* out = (float*)d_out;
    char* base = (char*)d_ws;
    const size_t MB = 1ull << 20;

    AllP P;
    P.bar = (u32*)base;                                    // 16 KB used (64 KB pad)
    P.decC = (float*)(base + 64 * 1024);                   // 2 MB
    char* Eu = base + 64 * 1024 + 2 * MB;                  // 12 MB union
    P.encC = (float*)Eu;                                   // enc: 4 MB
    P.encHh = (u16*)(Eu + 4 * MB);                         // enc: 4 MB
    P.encHl = (u16*)(Eu + 8 * MB);                         // enc: 4 MB
    P.CGf = (float*)Eu;                                    // dec: 8 MB (over encC+encHh)
    P.decHh = (u16*)(Eu + 8 * MB);                         // dec: 2 MB (over encHl)
    P.decHl = (u16*)(Eu + 10 * MB);                        // dec: 2 MB
    char* p = Eu + 12 * MB;
    P.HXYh = (u16*)p; p += 2 * MB;
    P.HXYl = (u16*)p; p += 2 * MB;
    P.H1h = (u16*)p; p += 2 * MB;
    P.H1l = (u16*)p; p += 2 * MB;
    P.H2h = (u16*)p; p += 1 * MB;
    P.H2l = (u16*)p; p += 1 * MB;
    P.muh = (u16*)p; p += 256 * 1024;
    P.mul2 = (u16*)p; p += 256 * 1024;
    P.Ydh = (u16*)p; p += 128 * 1024;
    P.Ydl = (u16*)p; p += 128 * 1024;
    u16* Xh = (u16*)p; p += 8 * MB;
    u16* Xl = (u16*)p; p += 8 * MB;
    u16* Yh = (u16*)p; p += (size_t)100 * 1024 * 64 * 2;
    u16* Yl = (u16*)p; p += (size_t)100 * 1024 * 64 * 2;
    u16* W0 = (u16*)p;

    size_t wo = 0;
    auto walloc = [&](size_t elems) { u16* q = W0 + wo; wo += elems * 2; return q; };
    u16* WPX0 = walloc((size_t)1024 * 320);
    u16* WPX1 = walloc((size_t)1024 * 320);
    u16* WPE0 = walloc((size_t)1024 * 320);
    u16* WPE1 = walloc((size_t)1024 * 320);
    u16* WPM1 = walloc((size_t)1024 * 1024);
    u16* WPM2 = walloc((size_t)512 * 1024);
    u16* WPMU = walloc((size_t)128 * 512);
    u16* WPLV = walloc((size_t)128 * 512);
    u16* WPCG = walloc((size_t)2048 * 640);
    u16* WPDG = walloc((size_t)2048 * 576);
    u16* WPD1 = walloc((size_t)1024 * 512);
    u16* WPD2 = walloc((size_t)512 * 1024);
    u16* WPDO = walloc((size_t)64 * 512);

    auto prep = [&](const float* s1, int ld1, int k1, const float* s2, int ld2,
                    u16* o, int N, int KT) {
        prep_w<<<(N * KT / 8) / 256, 256, 0, stream>>>(s1, ld1, k1, s2, ld2, o, N / 16);
    };
    prep(F(2), 64, 64, F(3), 256, WPX0, 1024, 320);
    prep(F(6), 64, 64, F(7), 256, WPX1, 1024, 320);
    prep(F(10), 64, 64, F(11), 256, WPE0, 1024, 320);
    prep(F(14), 64, 64, F(15), 256, WPE1, 1024, 320);
    prep(F(18), 1024, 1024, F(18), 1024, WPM1, 1024, 1024);
    prep(F(20), 1024, 1024, F(20), 1024, WPM2, 512, 1024);
    prep(F(22), 512, 512, F(22), 512, WPMU, 128, 512);
    prep(F(24), 512, 512, F(24), 512, WPLV, 128, 512);
    prep(F(26), 704, 640, F(26), 704, WPCG, 2048, 640);
    prep(F(26) + 640, 704, 64, F(27), 512, WPDG, 2048, 576);
    prep(F(30), 512, 512, F(30), 512, WPD1, 1024, 512);
    prep(F(32), 1024, 1024, F(32), 1024, WPD2, 512, 1024);
    prep(F(34), 512, 512, F(34), 512, WPDO, 64, 512);

    prep_act<<<4096, 256, 0, stream>>>(x, Xh, Xl, 64 * 1024 * 64 / 4);
    prep_act<<<6400, 256, 0, stream>>>(y, Yh, Yl, 100 * 1024 * 64 / 4);

    hipMemsetAsync(P.bar, 0, 64 * 1024, stream);

    P.Xh = Xh; P.Xl = Xl; P.Yh = Yh; P.Yl = Yl;
    const int wi[4] = {2, 6, 10, 14};
    u16* wps[4] = {WPX0, WPX1, WPE0, WPE1};
    for (int s = 0; s < 4; ++s) {
        P.Wenc[s] = wps[s];
        P.ebi[s] = F(wi[s] + 2);
        P.ebh[s] = F(wi[s] + 3);
    }
    P.Wm1 = WPM1; P.Wm2 = WPM2; P.Wmu = WPMU; P.Wlv = WPLV;
    P.Wcg = WPCG; P.Wdg = WPDG; P.Wd1 = WPD1; P.Wd2 = WPD2; P.Wdo = WPDO;
    P.b19 = F(19); P.b21 = F(21); P.b23 = F(23); P.b25 = F(25);
    P.b28 = F(28); P.b29 = F(29); P.b31 = F(31); P.b33 = F(33); P.b35 = F(35);
    P.outY = out;
    P.muF = out + (size_t)100 * 1024 * 64;
    P.lvF = P.muF + (size_t)1024 * 128;

    vae_persist<<<256, 512, 0, stream>>>(P);
}

// Round 5
// 13881.659 us; speedup vs baseline: 3.3925x; 3.3925x over previous
//
#include <hip/hip_runtime.h>

typedef unsigned short u16;
typedef unsigned int u32;
typedef __attribute__((ext_vector_type(8))) short s16x8;
typedef __attribute__((ext_vector_type(4))) float f32x4;

#define MFMA_BF16 __builtin_amdgcn_mfma_f32_16x16x32_bf16
#define SCOPE_AGT __HIP_MEMORY_SCOPE_AGENT

__device__ __forceinline__ float sigf(float x) { return 1.f / (1.f + __expf(-x)); }
__device__ __forceinline__ float tanh_fast(float x) {
    float e = __expf(2.f * x);
    return 1.f - 2.f / (e + 1.f);
}
__device__ __forceinline__ u16 bf16_rn(float x) {
    u32 u = __float_as_uint(x);
    u += 0x7FFFu + ((u >> 16) & 1u);
    return (u16)(u >> 16);
}
__device__ __forceinline__ void split_store(float v, u16* __restrict__ ph,
                                            u16* __restrict__ pl, size_t off) {
    u16 h = bf16_rn(v);
    float hf = __uint_as_float(((u32)h) << 16);
    ph[off] = h;
    pl[off] = bf16_rn(v - hf);
}
__device__ __forceinline__ void mma3(f32x4& acc, s16x8 ah, s16x8 al, s16x8 wh, s16x8 wl) {
    acc = MFMA_BF16(ah, wh, acc, 0, 0, 0);
    acc = MFMA_BF16(al, wh, acc, 0, 0, 0);
    acc = MFMA_BF16(ah, wl, acc, 0, 0, 0);
}

// ---------------- weight prep: fragment-linear bf16 hi/lo ----------------
__global__ __launch_bounds__(256) void prep_w(const float* __restrict__ S1, int ld1, int K1,
                                              const float* __restrict__ S2, int ld2,
                                              u16* __restrict__ out, int NF) {
    int idx = blockIdx.x * 256 + threadIdx.x;
    int l = idx & 63;
    int sf = idx >> 6;
    int f = sf % NF;
    int s = sf / NF;
    int n = f * 16 + (l & 15);
    int kb = s * 32 + ((l >> 4) << 3);
    u16* o = out + (size_t)idx * 16;
#pragma unroll
    for (int j = 0; j < 8; ++j) {
        int k = kb + j;
        float v = (k < K1) ? S1[(size_t)n * ld1 + k] : S2[(size_t)n * ld2 + (k - K1)];
        u16 h = bf16_rn(v);
        float hf = __uint_as_float(((u32)h) << 16);
        o[j] = h;
        o[8 + j] = bf16_rn(v - hf);
    }
}

// ---------------- activation prep: f32 -> hi/lo planes ----------------
__global__ __launch_bounds__(256) void prep_act(const float* __restrict__ in,
                                                u16* __restrict__ hi, u16* __restrict__ lo,
                                                int n4) {
    int i = blockIdx.x * 256 + threadIdx.x;
    if (i >= n4) return;
    float4 v = ((const float4*)in)[i];
    float vv[4] = {v.x, v.y, v.z, v.w};
    u16 h[4], lw[4];
#pragma unroll
    for (int j = 0; j < 4; ++j) {
        h[j] = bf16_rn(vv[j]);
        float hf = __uint_as_float(((u32)h[j]) << 16);
        lw[j] = bf16_rn(vv[j] - hf);
    }
    ((ushort4*)hi)[i] = make_ushort4(h[0], h[1], h[2], h[3]);
    ((ushort4*)lo)[i] = make_ushort4(lw[0], lw[1], lw[2], lw[3]);
}

// ---------------- fast device-wide / group barrier ----------------
// Relaxed polls (no cache invalidation per iter) + one acquire fence at exit.
// Aggregator block (first of group): wave0 polls all member flags, publishes gen.
__device__ __forceinline__ void bar_sync(u32* __restrict__ flags, u32* __restrict__ gen,
                                         int ngen, int first, int count, u32 k) {
    __syncthreads();
    if (threadIdx.x == 0) {
        __builtin_amdgcn_fence(__ATOMIC_RELEASE, "agent");
        __hip_atomic_store(&flags[blockIdx.x * 16], k, __ATOMIC_RELAXED, SCOPE_AGT);
    }
    if ((int)blockIdx.x == first) {
        if (threadIdx.x < 64) {
            int nper = (count + 63) >> 6;
            for (;;) {
                u32 mn = 0xFFFFFFFFu;
                for (int j = 0; j < nper; ++j) {
                    int idx = (int)threadIdx.x * nper + j;
                    if (idx < count) {
                        u32 v = __hip_atomic_load(&flags[(first + idx) * 16],
                                                  __ATOMIC_RELAXED, SCOPE_AGT);
                        mn = (v < mn) ? v : mn;
                    }
                }
                if (__all((int)(mn >= k))) break;
                __builtin_amdgcn_s_sleep(1);
            }
            __builtin_amdgcn_fence(__ATOMIC_ACQUIRE, "agent");
        }
        __syncthreads();
        if ((int)threadIdx.x < ngen)
            __hip_atomic_store(&gen[threadIdx.x * 16], k, __ATOMIC_RELEASE, SCOPE_AGT);
    } else {
        if (threadIdx.x == 0) {
            u32* g = &gen[(ngen > 1 ? (int)(blockIdx.x & 7) : 0) * 16];
            while (__hip_atomic_load(g, __ATOMIC_RELAXED, SCOPE_AGT) < k)
                __builtin_amdgcn_s_sleep(8);
            __builtin_amdgcn_fence(__ATOMIC_ACQUIRE, "agent");
        }
    }
    __syncthreads();
}

// ---------------- params ----------------
struct AllP {
    const u16 *Xh, *Xl, *Yh, *Yl;
    const float* ebi[4];
    const float* ebh[4];
    const float *b19, *b21, *b23, *b25, *b28, *b29, *b31, *b33, *b35;
    const u16* Wenc[4];
    const u16 *Wm1, *Wm2, *Wmu, *Wlv, *Wcg, *Wdg, *Wd1, *Wd2, *Wdo;
    u16 *encHh, *encHl;
    float* encC;
    u16 *HXYh, *HXYl, *H1h, *H1l, *H2h, *H2l, *muh, *mul2, *Ydh, *Ydl, *decHh, *decHl;
    float *CGf, *decC;
    float *outY, *muF, *lvF;
    u32 *flags, *genG, *genE;
};

// ---------------- generic GEMM phase: wave owns row-tile rt, cols ct*CF*16 ----------------
template <int CF, int ACT>
__device__ __forceinline__ void phase_gemm2(
    int NC, int rt, int ct0, int l, int lr, int lk8, int l4,
    const u16* __restrict__ A1h, const u16* __restrict__ A1l, int ld1, int K1,
    const u16* __restrict__ A2h, const u16* __restrict__ A2l, int ld2,
    const u16* __restrict__ Wp, int NF, int NS,
    const float* __restrict__ b1, const float* __restrict__ b2,
    float* __restrict__ outF, int ldo,
    u16* __restrict__ Oh, u16* __restrict__ Ol, int ldop) {
    const s16x8* wp = (const s16x8*)Wp;
    const int row = rt * 16 + lr;
    for (int ct = ct0; ct < NC; ct += 32) {
        f32x4 acc[CF];
#pragma unroll
        for (int cf = 0; cf < CF; ++cf) acc[cf] = (f32x4){0.f, 0.f, 0.f, 0.f};
        for (int s = 0; s < NS; ++s) {
            int kb = s * 32 + lk8;
            const u16 *ph, *pl2;
            size_t off;
            if (kb < K1) { ph = A1h; pl2 = A1l; off = (size_t)row * ld1 + kb; }
            else { ph = A2h; pl2 = A2l; off = (size_t)row * ld2 + (kb - K1); }
            s16x8 ah = *(const s16x8*)(ph + off), al = *(const s16x8*)(pl2 + off);
#pragma unroll
            for (int cf = 0; cf < CF; ++cf) {
                size_t wi = ((size_t)(s * NF + ct * CF + cf) * 64 + l) * 2;
                mma3(acc[cf], ah, al, wp[wi], wp[wi + 1]);
            }
        }
#pragma unroll
        for (int cf = 0; cf < CF; ++cf) {
            int col = ct * CF * 16 + cf * 16 + lr;
            float bv = (b1 ? b1[col] : 0.f) + (b2 ? b2[col] : 0.f);
#pragma unroll
            for (int r = 0; r < 4; ++r) {
                float v = acc[cf][r] + bv;
                if (ACT) v = tanh_fast(v);
                int rw = rt * 16 + l4 + r;
                if (outF) outF[(size_t)rw * ldo + col] = v;
                if (Oh) split_store(v, Oh, Ol, (size_t)rw * ldop + col);
            }
        }
    }
}

// ---------------- the persistent kernel ----------------
__global__ __launch_bounds__(512, 2) void vae_persist(AllP P) {
    const int tid = threadIdx.x, b = blockIdx.x;
    const int wid = tid >> 6, l = tid & 63;
    const int lr = l & 15, lk8 = (l >> 4) * 8, l4 = (l >> 4) * 4;
    const int rt = (((b >> 3) & 7) << 3) + wid;        // 0..63 row tile
    const int ctbase = (b & 7) * 4 + (b >> 6);         // 0..31, XCD-local slices

    // ================= encoder (4 independent scan groups of 64 blocks) =================
    {
        const int scan = b >> 6;
        const int ct = b & 7;
        const int T = (scan < 2) ? 64 : 100;
        const int rev = scan & 1;
        const u16* Xh_ = (scan < 2) ? P.Xh : P.Yh;
        const u16* Xl_ = (scan < 2) ? P.Xl : P.Yl;
        const s16x8* wp = (const s16x8*)P.Wenc[scan];
        const float* bi = P.ebi[scan];
        const float* bh = P.ebh[scan];
        u16* Hhb = P.encHh + (size_t)scan * 2 * 1024 * 256;
        u16* Hlb = P.encHl + (size_t)scan * 2 * 1024 * 256;
        float* Cs = P.encC + (size_t)scan * 1024 * 256;
        const int row = rt * 16 + lr;
        const int hc0 = ct * 32;
        float hsr[2][4] = {};

        for (int t = 0; t < T; ++t) {
            int tt = rev ? (T - 1 - t) : t;
            const u16* xh = Xh_ + (size_t)tt * 1024 * 64;
            const u16* xl = Xl_ + (size_t)tt * 1024 * 64;
            const u16* Hch = Hhb + (size_t)(t & 1) * 1024 * 256;
            const u16* Hcl = Hlb + (size_t)(t & 1) * 1024 * 256;
            u16* Hnh = Hhb + (size_t)((t + 1) & 1) * 1024 * 256;
            u16* Hnl = Hlb + (size_t)((t + 1) & 1) * 1024 * 256;
            f32x4 acc[4][2];
#pragma unroll
            for (int q = 0; q < 4; ++q)
#pragma unroll
                for (int cf = 0; cf < 2; ++cf) {
                    int col = q * 256 + hc0 + cf * 16 + lr;
                    float bv = bi[col] + bh[col];
                    acc[q][cf] = (f32x4){bv, bv, bv, bv};
                }
            int NS = (t == 0) ? 2 : 10;
            for (int s = 0; s < NS; ++s) {
                int kb = s * 32 + lk8;
                const u16 *ph, *pl2;
                size_t off;
                if (kb < 64) { ph = xh; pl2 = xl; off = (size_t)row * 64 + kb; }
                else { ph = Hch; pl2 = Hcl; off = (size_t)row * 256 + (kb - 64); }
                s16x8 ah = *(const s16x8*)(ph + off), al = *(const s16x8*)(pl2 + off);
#pragma unroll
                for (int q = 0; q < 4; ++q)
#pragma unroll
                    for (int cf = 0; cf < 2; ++cf) {
                        size_t wi = ((size_t)(s * 64 + q * 16 + ct * 2 + cf) * 64 + l) * 2;
                        mma3(acc[q][cf], ah, al, wp[wi], wp[wi + 1]);
                    }
            }
#pragma unroll
            for (int cf = 0; cf < 2; ++cf) {
                int hc = hc0 + cf * 16 + lr;
#pragma unroll
                for (int r = 0; r < 4; ++r) {
                    int rw = rt * 16 + l4 + r;
                    size_t co = (size_t)rw * 256 + hc;
                    float gi = sigf(acc[0][cf][r]);
                    float gf = sigf(acc[1][cf][r]);
                    float gg = tanh_fast(acc[2][cf][r]);
                    float go = sigf(acc[3][cf][r]);
                    float cold = (t == 0) ? 0.f : Cs[co];
                    float cn = gf * cold + gi * gg;
                    float hn = go * tanh_fast(cn);
                    Cs[co] = cn;
                    split_store(hn, Hnh, Hnl, co);
                    hsr[cf][r] += hn;
                }
            }
            bar_sync(P.flags, P.genE + scan * 16, 1, scan * 64, 64, (u32)(t + 1));
        }
        float sc = (scan < 2) ? (1.f / 64.f) : (1.f / 100.f);
#pragma unroll
        for (int cf = 0; cf < 2; ++cf) {
            int hc = hc0 + cf * 16 + lr;
#pragma unroll
            for (int r = 0; r < 4; ++r) {
                int rw = rt * 16 + l4 + r;
                split_store(hsr[cf][r] * sc, P.HXYh, P.HXYl,
                            (size_t)rw * 1024 + scan * 256 + hc);
            }
        }
    }
    bar_sync(P.flags, P.genG, 8, 0, 256, 128);

    // ================= encoder MLP + heads + CG =================
    phase_gemm2<2, 1>(32, rt, ctbase, l, lr, lk8, l4,
                      P.HXYh, P.HXYl, 1024, 2048, P.HXYh, P.HXYl, 1024,
                      P.Wm1, 64, 32, P.b19, nullptr,
                      nullptr, 0, P.H1h, P.H1l, 1024);
    bar_sync(P.flags, P.genG, 8, 0, 256, 129);
    phase_gemm2<2, 1>(16, rt, ctbase, l, lr, lk8, l4,
                      P.H1h, P.H1l, 1024, 2048, P.H1h, P.H1l, 1024,
                      P.Wm2, 32, 32, P.b21, nullptr,
                      nullptr, 0, P.H2h, P.H2l, 512);
    bar_sync(P.flags, P.genG, 8, 0, 256, 130);
    if (ctbase < 4)
        phase_gemm2<2, 0>(4, rt, ctbase, l, lr, lk8, l4,
                          P.H2h, P.H2l, 512, 2048, P.H2h, P.H2l, 512,
                          P.Wmu, 8, 16, P.b23, nullptr,
                          P.muF, 128, P.muh, P.mul2, 128);
    else if (ctbase < 8)
        phase_gemm2<2, 0>(4, rt, ctbase - 4, l, lr, lk8, l4,
                          P.H2h, P.H2l, 512, 2048, P.H2h, P.H2l, 512,
                          P.Wlv, 8, 16, P.b25, nullptr,
                          P.lvF, 128, nullptr, nullptr, 0);
    bar_sync(P.flags, P.genG, 8, 0, 256, 131);
    phase_gemm2<2, 0>(64, rt, ctbase, l, lr, lk8, l4,
                      P.HXYh, P.HXYl, 1024, 512, P.muh, P.mul2, 128,
                      P.Wcg, 128, 20, P.b28, P.b29,
                      P.CGf, 2048, nullptr, nullptr, 0);
    bar_sync(P.flags, P.genG, 8, 0, 256, 132);

    // ================= decoder =================
    {
        const int hct = ctbase;            // 0..31
        const int row = rt * 16 + lr;
        const int hc = hct * 16 + lr;
        const s16x8* wp = (const s16x8*)P.Wdg;

        for (int t = 0; t < 100; ++t) {
            // ---- gates + cell ----
            {
                const u16* yph = (t == 0) ? (P.Xh + (size_t)63 * 1024 * 64) : P.Ydh;
                const u16* ypl = (t == 0) ? (P.Xl + (size_t)63 * 1024 * 64) : P.Ydl;
                const u16* Hch = P.decHh + (size_t)(t & 1) * 1024 * 512;
                const u16* Hcl = P.decHl + (size_t)(t & 1) * 1024 * 512;
                u16* Hnh = P.decHh + (size_t)((t + 1) & 1) * 1024 * 512;
                u16* Hnl = P.decHl + (size_t)((t + 1) & 1) * 1024 * 512;
                f32x4 acc[4];
#pragma unroll
                for (int q = 0; q < 4; ++q)
#pragma unroll
                    for (int r = 0; r < 4; ++r)
                        acc[q][r] = P.CGf[(size_t)(rt * 16 + l4 + r) * 2048 +
                                          q * 512 + hct * 16 + lr];
                int NS = (t == 0) ? 2 : 18;
                for (int s = 0; s < NS; ++s) {
                    int kb = s * 32 + lk8;
                    const u16 *ph, *pl2;
                    size_t off;
                    if (kb < 64) { ph = yph; pl2 = ypl; off = (size_t)row * 64 + kb; }
                    else { ph = Hch; pl2 = Hcl; off = (size_t)row * 512 + (kb - 64); }
                    s16x8 ah = *(const s16x8*)(ph + off), al = *(const s16x8*)(pl2 + off);
#pragma unroll
                    for (int q = 0; q < 4; ++q) {
                        size_t wi = ((size_t)(s * 128 + q * 32 + hct) * 64 + l) * 2;
                        mma3(acc[q], ah, al, wp[wi], wp[wi + 1]);
                    }
                }
#pragma unroll
                for (int r = 0; r < 4; ++r) {
                    int rw = rt * 16 + l4 + r;
                    size_t co = (size_t)rw * 512 + hc;
                    float gi = sigf(acc[0][r]);
                    float gf = sigf(acc[1][r]);
                    float gg = tanh_fast(acc[2][r]);
                    float go = sigf(acc[3][r]);
                    float cold = (t == 0) ? 0.f : P.decC[co];
                    float cn = gf * cold + gi * gg;
                    float hn = go * tanh_fast(cn);
                    P.decC[co] = cn;
                    split_store(hn, Hnh, Hnl, co);
                }
            }
            bar_sync(P.flags, P.genG, 8, 0, 256, (u32)(133 + t * 4));
            const u16* Hnh = P.decHh + (size_t)((t + 1) & 1) * 1024 * 512;
            const u16* Hnl = P.decHl + (size_t)((t + 1) & 1) * 1024 * 512;
            phase_gemm2<2, 1>(32, rt, ctbase, l, lr, lk8, l4,
                              Hnh, Hnl, 512, 2048, Hnh, Hnl, 512,
                              P.Wd1, 64, 16, P.b31, nullptr,
                              nullptr, 0, P.H1h, P.H1l, 1024);
            bar_sync(P.flags, P.genG, 8, 0, 256, (u32)(134 + t * 4));
            phase_gemm2<2, 1>(16, rt, ctbase, l, lr, lk8, l4,
                              P.H1h, P.H1l, 1024, 2048, P.H1h, P.H1l, 1024,
                              P.Wd2, 32, 32, P.b33, nullptr,
                              nullptr, 0, P.H2h, P.H2l, 512);
            bar_sync(P.flags, P.genG, 8, 0, 256, (u32)(135 + t * 4));
            if (ctbase < 2)
                phase_gemm2<2, 0>(2, rt, ctbase, l, lr, lk8, l4,
                                  P.H2h, P.H2l, 512, 2048, P.H2h, P.H2l, 512,
                                  P.Wdo, 4, 16, P.b35, nullptr,
                                  P.outY + (size_t)t * 1024 * 64, 64, P.Ydh, P.Ydl, 64);
            if (t < 99)
                bar_sync(P.flags, P.genG, 8, 0, 256, (u32)(136 + t * 4));
        }
    }
}

// ---------------- host ----------------
extern "C" void kernel_launch(void* const* d_in, const int* in_sizes, int n_in,
                              void* d_out, int out_size, void* d_ws, size_t ws_size,
                              hipStream_t stream) {
    (void)in_sizes; (void)n_in; (void)out_size; (void)ws_size;
    auto F = [&](int i) { return (const float*)d_in[i]; };
    const float* x = F(0);
    const float* y = F(1);
    float* out = (float*)d_out;
    char* base = (char*)d_ws;
    const size_t MB = 1ull << 20;

    AllP P;
    P.flags = (u32*)base;                                  // 16 KB
    P.genG = (u32*)(base + 16 * 1024);                     // 512 B
    P.genE = (u32*)(base + 16 * 1024 + 512);               // 256 B
    P.decC = (float*)(base + 64 * 1024);                   // 2 MB
    char* Eu = base + 64 * 1024 + 2 * MB;                  // 12 MB union
    P.encC = (float*)Eu;                                   // enc: 4 MB
    P.encHh = (u16*)(Eu + 4 * MB);                         // enc: 4 MB
    P.encHl = (u16*)(Eu + 8 * MB);                         // enc: 4 MB
    P.CGf = (float*)Eu;                                    // dec: 8 MB
    P.decHh = (u16*)(Eu + 8 * MB);                         // dec: 2 MB
    P.decHl = (u16*)(Eu + 10 * MB);                        // dec: 2 MB
    char* p = Eu + 12 * MB;
    P.HXYh = (u16*)p; p += 2 * MB;
    P.HXYl = (u16*)p; p += 2 * MB;
    P.H1h = (u16*)p; p += 2 * MB;
    P.H1l = (u16*)p; p += 2 * MB;
    P.H2h = (u16*)p; p += 1 * MB;
    P.H2l = (u16*)p; p += 1 * MB;
    P.muh = (u16*)p; p += 256 * 1024;
    P.mul2 = (u16*)p; p += 256 * 1024;
    P.Ydh = (u16*)p; p += 128 * 1024;
    P.Ydl = (u16*)p; p += 128 * 1024;
    u16* Xh = (u16*)p; p += 8 * MB;
    u16* Xl = (u16*)p; p += 8 * MB;
    u16* Yh = (u16*)p; p += (size_t)100 * 1024 * 64 * 2;
    u16* Yl = (u16*)p; p += (size_t)100 * 1024 * 64 * 2;
    u16* W0 = (u16*)p;

    size_t wo = 0;
    auto walloc = [&](size_t elems) { u16* q = W0 + wo; wo += elems * 2; return q; };
    u16* WPX0 = walloc((size_t)1024 * 320);
    u16* WPX1 = walloc((size_t)1024 * 320);
    u16* WPE0 = walloc((size_t)1024 * 320);
    u16* WPE1 = walloc((size_t)1024 * 320);
    u16* WPM1 = walloc((size_t)1024 * 1024);
    u16* WPM2 = walloc((size_t)512 * 1024);
    u16* WPMU = walloc((size_t)128 * 512);
    u16* WPLV = walloc((size_t)128 * 512);
    u16* WPCG = walloc((size_t)2048 * 640);
    u16* WPDG = walloc((size_t)2048 * 576);
    u16* WPD1 = walloc((size_t)1024 * 512);
    u16* WPD2 = walloc((size_t)512 * 1024);
    u16* WPDO = walloc((size_t)64 * 512);

    auto prep = [&](const float* s1, int ld1, int k1, const float* s2, int ld2,
                    u16* o, int N, int KT) {
        prep_w<<<(N * KT / 8) / 256, 256, 0, stream>>>(s1, ld1, k1, s2, ld2, o, N / 16);
    };
    prep(F(2), 64, 64, F(3), 256, WPX0, 1024, 320);
    prep(F(6), 64, 64, F(7), 256, WPX1, 1024, 320);
    prep(F(10), 64, 64, F(11), 256, WPE0, 1024, 320);
    prep(F(14), 64, 64, F(15), 256, WPE1, 1024, 320);
    prep(F(18), 1024, 1024, F(18), 1024, WPM1, 1024, 1024);
    prep(F(20), 1024, 1024, F(20), 1024, WPM2, 512, 1024);
    prep(F(22), 512, 512, F(22), 512, WPMU, 128, 512);
    prep(F(24), 512, 512, F(24), 512, WPLV, 128, 512);
    prep(F(26), 704, 640, F(26), 704, WPCG, 2048, 640);
    prep(F(26) + 640, 704, 64, F(27), 512, WPDG, 2048, 576);
    prep(F(30), 512, 512, F(30), 512, WPD1, 1024, 512);
    prep(F(32), 1024, 1024, F(32), 1024, WPD2, 512, 1024);
    prep(F(34), 512, 512, F(34), 512, WPDO, 64, 512);

    prep_act<<<4096, 256, 0, stream>>>(x, Xh, Xl, 64 * 1024 * 64 / 4);
    prep_act<<<6400, 256, 0, stream>>>(y, Yh, Yl, 100 * 1024 * 64 / 4);

    hipMemsetAsync(base, 0, 64 * 1024, stream);  // barrier flags + gens

    P.Xh = Xh; P.Xl = Xl; P.Yh = Yh; P.Yl = Yl;
    const int wi[4] = {2, 6, 10, 14};
    u16* wps[4] = {WPX0, WPX1, WPE0, WPE1};
    for (int s = 0; s < 4; ++s) {
        P.Wenc[s] = wps[s];
        P.ebi[s] = F(wi[s] + 2);
        P.ebh[s] = F(wi[s] + 3);
    }
    P.Wm1 = WPM1; P.Wm2 = WPM2; P.Wmu = WPMU; P.Wlv = WPLV;
    P.Wcg = WPCG; P.Wdg = WPDG; P.Wd1 = WPD1; P.Wd2 = WPD2; P.Wdo = WPDO;
    P.b19 = F(19); P.b21 = F(21); P.b23 = F(23); P.b25 = F(25);
    P.b28 = F(28); P.b29 = F(29); P.b31 = F(31); P.b33 = F(33); P.b35 = F(35);
    P.outY = out;
    P.muF = out + (size_t)100 * 1024 * 64;
    P.lvF = P.muF + (size_t)1024 * 128;

    vae_persist<<<256, 512, 0, stream>>>(P);
}